// Round 2
// baseline (385.099 us; speedup 1.0000x reference)
//
#include <hip/hip_runtime.h>
#include <math.h>

#define NF 32
#define NN 4096
#define ND 64
#define NK 512

// loss = q_latent + 0.25 * e_latent = 1.25 * mean((q - x)^2)
#define LOSS_SCALE (1.25f / (float)(NF * NN * ND))

// ---------------------------------------------------------------------------
// prep: wt[f][k][d] = w[f][d][k]   (contiguous d per codeword -> streamable)
//       w2h[f][k]   = 0.5 * ||w_k||^2
//       zero the loss slot (d_out is poisoned before every timed launch)
// ---------------------------------------------------------------------------
__global__ __launch_bounds__(256)
void vq_prep(const float* __restrict__ w, float* __restrict__ wt,
             float* __restrict__ w2h, float* __restrict__ loss_slot) {
    const int gid = blockIdx.x * 256 + threadIdx.x;   // [0, NF*NK)
    if (gid == 0) *loss_slot = 0.0f;
    const int f = gid >> 9;          // / NK
    const int k = gid & (NK - 1);
    const float* __restrict__ wf = w + (size_t)f * ND * NK;
    float v[ND];
    float s = 0.0f;
#pragma unroll
    for (int d = 0; d < ND; ++d) {
        v[d] = wf[d * NK + k];       // coalesced across lanes (consecutive k)
        s = fmaf(v[d], v[d], s);
    }
    float* __restrict__ o = wt + ((size_t)f * NK + k) * ND;
#pragma unroll
    for (int d4 = 0; d4 < ND / 4; ++d4) {
        *(float4*)(o + 4 * d4) =
            make_float4(v[4 * d4], v[4 * d4 + 1], v[4 * d4 + 2], v[4 * d4 + 3]);
    }
    w2h[gid] = 0.5f * s;
}

// ---------------------------------------------------------------------------
// main: per thread = one row. score_k = 0.5*||w_k||^2 - x.w_k (row-constant
// ||x||^2 omitted, overall scale 2 omitted -> same argmin, strict < keeps
// first-index tie-break). w is wave-uniform -> scalar (SMEM) loads, double-
// buffered in 8-d chunks over contiguous wt rows.
// ---------------------------------------------------------------------------

// load one chunk: 8 d-values for each of 4 consecutive codewords
#define LOADC(Bf, dc) do {                                      \
    Bf[0] = *(const float4*)(pw + 0 * ND + (dc));               \
    Bf[1] = *(const float4*)(pw + 0 * ND + (dc) + 4);           \
    Bf[2] = *(const float4*)(pw + 1 * ND + (dc));               \
    Bf[3] = *(const float4*)(pw + 1 * ND + (dc) + 4);           \
    Bf[4] = *(const float4*)(pw + 2 * ND + (dc));               \
    Bf[5] = *(const float4*)(pw + 2 * ND + (dc) + 4);           \
    Bf[6] = *(const float4*)(pw + 3 * ND + (dc));               \
    Bf[7] = *(const float4*)(pw + 3 * ND + (dc) + 4);           \
} while (0)

#define FMA8(t, q0, q1, dc) do {                                \
    t = fmaf(-x[(dc) + 0], q0.x, t);                            \
    t = fmaf(-x[(dc) + 1], q0.y, t);                            \
    t = fmaf(-x[(dc) + 2], q0.z, t);                            \
    t = fmaf(-x[(dc) + 3], q0.w, t);                            \
    t = fmaf(-x[(dc) + 4], q1.x, t);                            \
    t = fmaf(-x[(dc) + 5], q1.y, t);                            \
    t = fmaf(-x[(dc) + 6], q1.z, t);                            \
    t = fmaf(-x[(dc) + 7], q1.w, t);                            \
} while (0)

#define FMAC(Bf, dc) do {                                       \
    FMA8(t0, Bf[0], Bf[1], dc);                                 \
    FMA8(t1, Bf[2], Bf[3], dc);                                 \
    FMA8(t2, Bf[4], Bf[5], dc);                                 \
    FMA8(t3, Bf[6], Bf[7], dc);                                 \
} while (0)

__global__ __launch_bounds__(256)
void vq_main(const float* __restrict__ x_in, const float* __restrict__ wt,
             const float* __restrict__ w2h, float* __restrict__ out) {
    const int f = blockIdx.y;
    const int n = blockIdx.x * 256 + threadIdx.x;

    const float* __restrict__ wtf = wt + (size_t)f * NK * ND;
    const float* __restrict__ xr  = x_in + ((size_t)f * NN + n) * ND;

    __shared__ float w2s[NK];
    for (int k = threadIdx.x; k < NK; k += 256) w2s[k] = w2h[f * NK + k];
    __syncthreads();

    float x[ND];
#pragma unroll
    for (int d4 = 0; d4 < ND / 4; ++d4) {
        float4 v = *(const float4*)(xr + 4 * d4);
        x[4 * d4 + 0] = v.x;
        x[4 * d4 + 1] = v.y;
        x[4 * d4 + 2] = v.z;
        x[4 * d4 + 3] = v.w;
    }

    float best = INFINITY;
    int bidx = 0;

    for (int k0 = 0; k0 < NK; k0 += 4) {
        const float* __restrict__ pw = wtf + (size_t)k0 * ND;  // 1KB contiguous
        float t0 = w2s[k0 + 0];
        float t1 = w2s[k0 + 1];
        float t2 = w2s[k0 + 2];
        float t3 = w2s[k0 + 3];

        float4 A[8], B[8];
        // software pipeline: load chunk i+1 while FMAing chunk i
        LOADC(A, 0);
        LOADC(B, 8);
        FMAC(A, 0);
        LOADC(A, 16);
        FMAC(B, 8);
        LOADC(B, 24);
        FMAC(A, 16);
        LOADC(A, 32);
        FMAC(B, 24);
        LOADC(B, 40);
        FMAC(A, 32);
        LOADC(A, 48);
        FMAC(B, 40);
        LOADC(B, 56);
        FMAC(A, 48);
        FMAC(B, 56);

        if (t0 < best) { best = t0; bidx = k0 + 0; }
        if (t1 < best) { best = t1; bidx = k0 + 1; }
        if (t2 < best) { best = t2; bidx = k0 + 2; }
        if (t3 < best) { best = t3; bidx = k0 + 3; }
    }

    // ---- epilogue: gather codeword (contiguous in wt!), write out, loss ----
    float lsum = 0.0f;
    const float* __restrict__ qrow = wtf + (size_t)bidx * ND;
    float* __restrict__ orow = out + ((size_t)f * NN + n) * ND;
#pragma unroll
    for (int d4 = 0; d4 < ND / 4; ++d4) {
        float4 q = *(const float4*)(qrow + 4 * d4);
        const float dx0 = q.x - x[4 * d4 + 0];
        const float dx1 = q.y - x[4 * d4 + 1];
        const float dx2 = q.z - x[4 * d4 + 2];
        const float dx3 = q.w - x[4 * d4 + 3];
        lsum = fmaf(dx0, dx0, lsum);
        lsum = fmaf(dx1, dx1, lsum);
        lsum = fmaf(dx2, dx2, lsum);
        lsum = fmaf(dx3, dx3, lsum);
        *(float4*)(orow + 4 * d4) = q;
    }

#pragma unroll
    for (int off = 32; off > 0; off >>= 1) {
        lsum += __shfl_down(lsum, off, 64);
    }
    if ((threadIdx.x & 63) == 0) {
        atomicAdd(out + (size_t)NF * NN * ND, lsum * LOSS_SCALE);
    }
}

extern "C" void kernel_launch(void* const* d_in, const int* in_sizes, int n_in,
                              void* d_out, int out_size, void* d_ws, size_t ws_size,
                              hipStream_t stream) {
    const float* x_in = (const float*)d_in[0];  // [F, N, D] fp32
    const float* w    = (const float*)d_in[1];  // [F, D, K] fp32
    float* out        = (float*)d_out;          // [F*N*D] output then [1] loss

    float* wt  = (float*)d_ws;                          // [F, K, D]  4 MB
    float* w2h = wt + (size_t)NF * NK * ND;             // [F, K]     64 KB

    vq_prep<<<NF * NK / 256, 256, 0, stream>>>(w, wt, w2h,
                                               out + (size_t)NF * NN * ND);

    dim3 grid(NN / 256, NF);
    vq_main<<<grid, 256, 0, stream>>>(x_in, wt, w2h, out);
}

// Round 3
// 305.074 us; speedup vs baseline: 1.2623x; 1.2623x over previous
//
#include <hip/hip_runtime.h>
#include <math.h>

#define NF 32
#define NN 4096
#define ND 64
#define NK 512
#define KSPLIT 4
#define KCH (NK / KSPLIT)   // 128 codewords per z-slice

// loss = q_latent + 0.25 * e_latent = 1.25 * mean((q - x)^2)
#define LOSS_SCALE (1.25f / (float)(NF * NN * ND))

// ---------------------------------------------------------------------------
// prep: wt[f][k][d] = w[f][d][k]; w2h[f][k] = 0.5*||w_k||^2;
//       keys[row] = UINT64_MAX; loss = 0.   (ws/out are poisoned each launch)
// grid: NF*NN/256 = 512 blocks
// ---------------------------------------------------------------------------
__global__ __launch_bounds__(256)
void vq_prep(const float* __restrict__ w, float* __restrict__ wt,
             float* __restrict__ w2h, unsigned long long* __restrict__ keys,
             float* __restrict__ loss_slot) {
    const int gid = blockIdx.x * 256 + threadIdx.x;   // [0, NF*NN)
    if (gid == 0) *loss_slot = 0.0f;
    keys[gid] = 0xFFFFFFFFFFFFFFFFULL;
    if (gid < NF * NK) {
        const int f = gid >> 9;          // / NK
        const int k = gid & (NK - 1);
        const float* __restrict__ wf = w + (size_t)f * ND * NK;
        float* __restrict__ o = wt + (size_t)gid * ND;
        float s = 0.0f;
#pragma unroll
        for (int d4 = 0; d4 < ND / 4; ++d4) {
            float4 v;
            v.x = wf[(4 * d4 + 0) * NK + k];   // coalesced across lanes (k)
            v.y = wf[(4 * d4 + 1) * NK + k];
            v.z = wf[(4 * d4 + 2) * NK + k];
            v.w = wf[(4 * d4 + 3) * NK + k];
            s = fmaf(v.x, v.x, s);
            s = fmaf(v.y, v.y, s);
            s = fmaf(v.z, v.z, s);
            s = fmaf(v.w, v.w, s);
            *(float4*)(o + 4 * d4) = v;
        }
        w2h[gid] = 0.5f * s;
    }
}

// ---------------------------------------------------------------------------
// argmin over a K-slice. score_k = 0.5*||w_k||^2 - x.w_k (row-constant ||x||^2
// and factor 2 omitted -> same argmin). Winner published via atomicMin on
// key = (monotone_enc(score) << 32) | k  -> exact global argmin with
// lowest-index tie-break.
// grid: (NN/256, NF, KSPLIT) = 2048 blocks; 4 blocks/CU resident -> 2 rounds.
// ---------------------------------------------------------------------------

#define LOADC(Bf, dc) do {                                      \
    Bf[0] = *(const float4*)(pw + 0 * ND + (dc));               \
    Bf[1] = *(const float4*)(pw + 0 * ND + (dc) + 4);           \
    Bf[2] = *(const float4*)(pw + 1 * ND + (dc));               \
    Bf[3] = *(const float4*)(pw + 1 * ND + (dc) + 4);           \
    Bf[4] = *(const float4*)(pw + 2 * ND + (dc));               \
    Bf[5] = *(const float4*)(pw + 2 * ND + (dc) + 4);           \
    Bf[6] = *(const float4*)(pw + 3 * ND + (dc));               \
    Bf[7] = *(const float4*)(pw + 3 * ND + (dc) + 4);           \
} while (0)

#define FMA8(t, q0, q1, dc) do {                                \
    t = fmaf(-x[(dc) + 0], q0.x, t);                            \
    t = fmaf(-x[(dc) + 1], q0.y, t);                            \
    t = fmaf(-x[(dc) + 2], q0.z, t);                            \
    t = fmaf(-x[(dc) + 3], q0.w, t);                            \
    t = fmaf(-x[(dc) + 4], q1.x, t);                            \
    t = fmaf(-x[(dc) + 5], q1.y, t);                            \
    t = fmaf(-x[(dc) + 6], q1.z, t);                            \
    t = fmaf(-x[(dc) + 7], q1.w, t);                            \
} while (0)

#define FMAC(Bf, dc) do {                                       \
    FMA8(t0, Bf[0], Bf[1], dc);                                 \
    FMA8(t1, Bf[2], Bf[3], dc);                                 \
    FMA8(t2, Bf[4], Bf[5], dc);                                 \
    FMA8(t3, Bf[6], Bf[7], dc);                                 \
} while (0)

__global__ __launch_bounds__(256, 4)
void vq_argmin(const float* __restrict__ x_in, const float* __restrict__ wt,
               const float* __restrict__ w2h,
               unsigned long long* __restrict__ keys) {
    const int f  = blockIdx.y;
    const int n  = blockIdx.x * 256 + threadIdx.x;
    const int ks = blockIdx.z * KCH;

    const float* __restrict__ wtf = wt + (size_t)f * NK * ND;
    const float* __restrict__ xr  = x_in + ((size_t)f * NN + n) * ND;

    __shared__ float w2s[KCH];
    if (threadIdx.x < KCH) w2s[threadIdx.x] = w2h[f * NK + ks + threadIdx.x];
    __syncthreads();

    // ---- x row into VGPRs, pinned there (opaque to the compiler) ----
    float x[ND];
#pragma unroll
    for (int d4 = 0; d4 < ND / 4; ++d4) {
        float4 v = *(const float4*)(xr + 4 * d4);
        x[4 * d4 + 0] = v.x;
        x[4 * d4 + 1] = v.y;
        x[4 * d4 + 2] = v.z;
        x[4 * d4 + 3] = v.w;
    }
#pragma unroll
    for (int d = 0; d < ND; ++d) asm volatile("" : "+v"(x[d]));

    float best = INFINITY;
    int bidx = ks;

    for (int kk = 0; kk < KCH; kk += 4) {
        const int k0 = ks + kk;
        const float* __restrict__ pw = wtf + (size_t)k0 * ND;  // 1KB contiguous
        float t0 = w2s[kk + 0];
        float t1 = w2s[kk + 1];
        float t2 = w2s[kk + 2];
        float t3 = w2s[kk + 3];

        float4 A[8], B[8];
        LOADC(A, 0);
        LOADC(B, 8);
        FMAC(A, 0);
        LOADC(A, 16);
        FMAC(B, 8);
        LOADC(B, 24);
        FMAC(A, 16);
        LOADC(A, 32);
        FMAC(B, 24);
        LOADC(B, 40);
        FMAC(A, 32);
        LOADC(A, 48);
        FMAC(B, 40);
        LOADC(B, 56);
        FMAC(A, 48);
        FMAC(B, 56);

        if (t0 < best) { best = t0; bidx = k0 + 0; }
        if (t1 < best) { best = t1; bidx = k0 + 1; }
        if (t2 < best) { best = t2; bidx = k0 + 2; }
        if (t3 < best) { best = t3; bidx = k0 + 3; }
    }

    // monotone float->uint encoding; key = enc << 32 | k
    unsigned int u = __float_as_uint(best);
    u ^= (unsigned int)(((int)u >> 31)) | 0x80000000u;
    const unsigned long long key =
        ((unsigned long long)u << 32) | (unsigned long long)bidx;
    atomicMin(&keys[(size_t)f * NN + n], key);
}

// ---------------------------------------------------------------------------
// gather: resolve winning index, emit quantized row (straight-through output)
// and the scalar loss. grid: NF*NN/256 = 512 blocks.
// ---------------------------------------------------------------------------
__global__ __launch_bounds__(256)
void vq_gather(const float* __restrict__ x_in, const float* __restrict__ wt,
               const unsigned long long* __restrict__ keys,
               float* __restrict__ out) {
    const int gid = blockIdx.x * 256 + threadIdx.x;   // row id [0, NF*NN)
    const int f = gid >> 12;                          // / NN
    const unsigned int k = (unsigned int)(keys[gid] & 0xFFFFFFFFu);

    const float* __restrict__ qrow = wt + ((size_t)f * NK + k) * ND;
    const float* __restrict__ xr   = x_in + (size_t)gid * ND;
    float* __restrict__ orow       = out + (size_t)gid * ND;

    float lsum = 0.0f;
#pragma unroll
    for (int d4 = 0; d4 < ND / 4; ++d4) {
        float4 q  = *(const float4*)(qrow + 4 * d4);
        float4 xv = *(const float4*)(xr + 4 * d4);
        const float dx0 = q.x - xv.x;
        const float dx1 = q.y - xv.y;
        const float dx2 = q.z - xv.z;
        const float dx3 = q.w - xv.w;
        lsum = fmaf(dx0, dx0, lsum);
        lsum = fmaf(dx1, dx1, lsum);
        lsum = fmaf(dx2, dx2, lsum);
        lsum = fmaf(dx3, dx3, lsum);
        *(float4*)(orow + 4 * d4) = q;
    }

#pragma unroll
    for (int off = 32; off > 0; off >>= 1) {
        lsum += __shfl_down(lsum, off, 64);
    }
    if ((threadIdx.x & 63) == 0) {
        atomicAdd(out + (size_t)NF * NN * ND, lsum * LOSS_SCALE);
    }
}

extern "C" void kernel_launch(void* const* d_in, const int* in_sizes, int n_in,
                              void* d_out, int out_size, void* d_ws, size_t ws_size,
                              hipStream_t stream) {
    const float* x_in = (const float*)d_in[0];  // [F, N, D] fp32
    const float* w    = (const float*)d_in[1];  // [F, D, K] fp32
    float* out        = (float*)d_out;          // [F*N*D] output then [1] loss

    float* wt  = (float*)d_ws;                               // [F,K,D] 4 MB
    float* w2h = wt + (size_t)NF * NK * ND;                  // [F,K]   64 KB
    unsigned long long* keys =
        (unsigned long long*)(w2h + (size_t)NF * NK);        // [F,N]   1 MB

    vq_prep<<<NF * NN / 256, 256, 0, stream>>>(
        w, wt, w2h, keys, out + (size_t)NF * NN * ND);

    dim3 grid(NN / 256, NF, KSPLIT);
    vq_argmin<<<grid, 256, 0, stream>>>(x_in, wt, w2h, keys);

    vq_gather<<<NF * NN / 256, 256, 0, stream>>>(x_in, wt, keys, out);
}